// Round 3
// baseline (335.899 us; speedup 1.0000x reference)
//
#include <hip/hip_runtime.h>

#define NEG_SLOPE 0.2f
#define EPSV 1e-16f

// Monotone f32 <-> u32 mapping so atomicMax(u32) implements float max.
__device__ __forceinline__ unsigned fenc(float f) {
    unsigned b = __float_as_uint(f);
    return b ^ ((b & 0x80000000u) ? 0xFFFFFFFFu : 0x80000000u);
}
__device__ __forceinline__ float fdec(unsigned u) {
    unsigned b = (u & 0x80000000u) ? (u ^ 0x80000000u) : ~u;
    return __uint_as_float(b);
}
#define FENC_NEG_INF 0x007FFFFFu   // fenc(-inf)

// Robustness: detect int64 vs int32 edge_index on device (identical results
// r1/r2 showed it's int32, but keep the cheap dual path).
__global__ void detect_idx_kernel(const unsigned* __restrict__ ei32,
                                  int* __restrict__ flag) {
    __shared__ int anynz;
    if (threadIdx.x == 0) anynz = 0;
    __syncthreads();
    unsigned v = ei32[2 * threadIdx.x + 1];
    if (v != 0u) anynz = 1;
    __syncthreads();
    if (threadIdx.x == 0) *flag = (anynz ? 0 : 1);   // 1 => int64
}

__device__ __forceinline__ void load_edge(const void* ei, int is64, int E,
                                          int e, int& trg, int& src) {
    if (is64) {
        const long long* p = (const long long*)ei;
        trg = (int)p[e];
        src = (int)p[(size_t)E + e];
    } else {
        const int* p = (const int*)ei;
        trg = p[e];
        src = p[E + e];
    }
}

// K1: per-node logits per head; zero nsum; init global-max slot.
__global__ void node_scores_kernel(const float* __restrict__ nf,
                                   const float* __restrict__ sfs,
                                   const float* __restrict__ sft,
                                   float* __restrict__ ss,
                                   float* __restrict__ st,
                                   float* __restrict__ nsum,
                                   unsigned* __restrict__ gmax,
                                   int NH) {
    int i = blockIdx.x * blockDim.x + threadIdx.x;
    if (i >= NH) return;
    if (i == 0) *gmax = FENC_NEG_INF;
    int h = i & 3;
    const float4* __restrict__ row = (const float4*)(nf + (size_t)i * 32);
    const float4* __restrict__ as  = (const float4*)(sfs + h * 32);
    const float4* __restrict__ at  = (const float4*)(sft + h * 32);
    float accs = 0.f, acct = 0.f;
#pragma unroll
    for (int q = 0; q < 8; ++q) {
        float4 v = row[q];
        float4 a = as[q];
        float4 b = at[q];
        accs += v.x * a.x + v.y * a.y + v.z * a.z + v.w * a.w;
        acct += v.x * b.x + v.y * b.y + v.z * b.z + v.w * b.w;
    }
    ss[i] = accs;
    st[i] = acct;
    nsum[i] = 0.f;
}

__device__ __forceinline__ float edge_lr(const void* ei, const int* flag,
                                         const float* ss, const float* st,
                                         int E, int e, int h, int* trg_out) {
    int trg, src;
    load_edge(ei, *flag, E, e, trg, src);
    if (trg_out) *trg_out = trg;
    float s = ss[src * 4 + h] + st[trg * 4 + h];
    return s > 0.f ? s : NEG_SLOPE * s;
}

// K2a: global max of leaky_relu(score) over all (e,h).
// REQUIRED: reference subtracts the GLOBAL max before exp, and the 1e-16
// denominator eps is only meaningful at that scale (groups whose max is
// >~37 below the global max get eps-dominated denominators -> att ~ 0).
__global__ void edge_max_kernel(const void* __restrict__ ei,
                                const int* __restrict__ flag,
                                const float* __restrict__ ss,
                                const float* __restrict__ st,
                                unsigned* __restrict__ gmax,
                                int E) {
    __shared__ float red[256];
    int i = blockIdx.x * blockDim.x + threadIdx.x;
    float lr = -__builtin_inff();
    if (i < E * 4) lr = edge_lr(ei, flag, ss, st, E, i >> 2, i & 3, nullptr);
    red[threadIdx.x] = lr;
    __syncthreads();
    for (int off = 128; off > 0; off >>= 1) {
        if (threadIdx.x < off)
            red[threadIdx.x] = fmaxf(red[threadIdx.x], red[threadIdx.x + off]);
        __syncthreads();
    }
    if (threadIdx.x == 0) atomicMax(gmax, fenc(red[0]));
}

// K2b: exp(lr - c) scatter-added into nsum[trg,h].
__global__ void edge_exp_sum_kernel(const void* __restrict__ ei,
                                    const int* __restrict__ flag,
                                    const float* __restrict__ ss,
                                    const float* __restrict__ st,
                                    const unsigned* __restrict__ gmax,
                                    float* __restrict__ nsum,
                                    int E) {
    int i = blockIdx.x * blockDim.x + threadIdx.x;
    if (i >= E * 4) return;
    float c = fdec(*gmax);
    int trg;
    float lr = edge_lr(ei, flag, ss, st, E, i >> 2, i & 3, &trg);
    atomicAdd(&nsum[trg * 4 + (i & 3)], __expf(lr - c));
}

// K3a: att = exp(lr - c) / (nsum[trg,h] + 1e-16), numerator recomputed with
// the identical instruction sequence as K2b.
__global__ void att_kernel(const void* __restrict__ ei,
                           const int* __restrict__ flag,
                           const float* __restrict__ ss,
                           const float* __restrict__ st,
                           const unsigned* __restrict__ gmax,
                           const float* __restrict__ nsum,
                           float* __restrict__ out,
                           int E) {
    int i = blockIdx.x * blockDim.x + threadIdx.x;
    if (i >= E * 4) return;
    float c = fdec(*gmax);
    int trg;
    float lr = edge_lr(ei, flag, ss, st, E, i >> 2, i & 3, &trg);
    out[i] = __expf(lr - c) / (nsum[trg * 4 + (i & 3)] + EPSV);
}

// K3b: gather node feature rows to edges; 32 lanes x float4 = 512B per edge.
__global__ void gather_feat_kernel(const void* __restrict__ ei,
                                   const int* __restrict__ flag,
                                   const float4* __restrict__ nf4,
                                   float4* __restrict__ out4,
                                   int E) {
    int t = blockIdx.x * blockDim.x + threadIdx.x;
    if (t >= E * 32) return;
    int e = t >> 5, q = t & 31;
    int src;
    if (*flag) {
        const long long* p = (const long long*)ei;
        src = (int)p[(size_t)E + e];
    } else {
        const int* p = (const int*)ei;
        src = p[E + e];
    }
    out4[(size_t)e * 32 + q] = nf4[(size_t)src * 32 + q];
}

extern "C" void kernel_launch(void* const* d_in, const int* in_sizes, int n_in,
                              void* d_out, int out_size, void* d_ws, size_t ws_size,
                              hipStream_t stream) {
    const float* nf  = (const float*)d_in[0];
    const float* sfs = (const float*)d_in[1];
    const float* sft = (const float*)d_in[2];
    const void*  ei  = d_in[3];

    const int NH = in_sizes[0] / 32;   // N*H (F = 32)
    const int E  = in_sizes[3] / 2;

    float* out = (float*)d_out;
    float* ws  = (float*)d_ws;
    float*    ss   = ws;
    float*    st   = ws + NH;
    float*    nsum = ws + 2 * (size_t)NH;
    int*      flag = (int*)(ws + 3 * (size_t)NH);
    unsigned* gmax = (unsigned*)(flag + 1);

    const int B = 256;

    detect_idx_kernel<<<1, 256, 0, stream>>>((const unsigned*)ei, flag);

    node_scores_kernel<<<(NH + B - 1) / B, B, 0, stream>>>(nf, sfs, sft, ss, st,
                                                           nsum, gmax, NH);

    edge_max_kernel<<<(E * 4 + B - 1) / B, B, 0, stream>>>(ei, flag, ss, st, gmax, E);

    edge_exp_sum_kernel<<<(E * 4 + B - 1) / B, B, 0, stream>>>(ei, flag, ss, st,
                                                               gmax, nsum, E);

    att_kernel<<<(E * 4 + B - 1) / B, B, 0, stream>>>(ei, flag, ss, st, gmax,
                                                      nsum, out, E);

    gather_feat_kernel<<<(E * 32 + B - 1) / B, B, 0, stream>>>(
        ei, flag, (const float4*)nf, (float4*)(out + (size_t)E * 4), E);
}

// Round 5
// 259.330 us; speedup vs baseline: 1.2953x; 1.2953x over previous
//
#include <hip/hip_runtime.h>

#define NEG_SLOPE 0.2f
#define EPSV 1e-16f

typedef float f32x4 __attribute__((ext_vector_type(4)));

// Monotone f32 <-> u32 mapping so atomicMax(u32) implements float max.
__device__ __forceinline__ unsigned fenc(float f) {
    unsigned b = __float_as_uint(f);
    return b ^ ((b & 0x80000000u) ? 0xFFFFFFFFu : 0x80000000u);
}
__device__ __forceinline__ float fdec(unsigned u) {
    unsigned b = (u & 0x80000000u) ? (u ^ 0x80000000u) : ~u;
    return __uint_as_float(b);
}
#define FENC_NEG_INF 0x007FFFFFu   // fenc(-inf)

// Detect int64 vs int32 edge_index on device (r3 evidence: int32; keep dual path).
__global__ void detect_idx_kernel(const unsigned* __restrict__ ei32,
                                  int* __restrict__ flag) {
    __shared__ int anynz;
    if (threadIdx.x == 0) anynz = 0;
    __syncthreads();
    unsigned v = ei32[2 * threadIdx.x + 1];
    if (v != 0u) anynz = 1;
    __syncthreads();
    if (threadIdx.x == 0) *flag = (anynz ? 0 : 1);   // 1 => int64
}

__device__ __forceinline__ void load_edge(const void* ei, int is64, int E,
                                          int e, int& trg, int& src) {
    if (is64) {
        const long long* p = (const long long*)ei;
        trg = (int)__builtin_nontemporal_load(&p[e]);
        src = (int)__builtin_nontemporal_load(&p[(size_t)E + e]);
    } else {
        const int* p = (const int*)ei;
        trg = __builtin_nontemporal_load(&p[e]);
        src = __builtin_nontemporal_load(&p[E + e]);
    }
}
__device__ __forceinline__ int load_trg(const void* ei, int is64, int e) {
    if (is64) return (int)__builtin_nontemporal_load(&((const long long*)ei)[e]);
    return __builtin_nontemporal_load(&((const int*)ei)[e]);
}

// K1: per-node logits per head; zero nsum; init global-max slot.
__global__ void node_scores_kernel(const float* __restrict__ nf,
                                   const float* __restrict__ sfs,
                                   const float* __restrict__ sft,
                                   float* __restrict__ ss,
                                   float* __restrict__ st,
                                   float* __restrict__ nsum,
                                   unsigned* __restrict__ gmax,
                                   int NH) {
    int i = blockIdx.x * blockDim.x + threadIdx.x;
    if (i >= NH) return;
    if (i == 0) *gmax = FENC_NEG_INF;
    int h = i & 3;
    const float4* __restrict__ row = (const float4*)(nf + (size_t)i * 32);
    const float4* __restrict__ as  = (const float4*)(sfs + h * 32);
    const float4* __restrict__ at  = (const float4*)(sft + h * 32);
    float accs = 0.f, acct = 0.f;
#pragma unroll
    for (int q = 0; q < 8; ++q) {
        float4 v = row[q];
        float4 a = as[q];
        float4 b = at[q];
        accs += v.x * a.x + v.y * a.y + v.z * a.z + v.w * a.w;
        acct += v.x * b.x + v.y * b.y + v.z * b.z + v.w * b.w;
    }
    ss[i] = accs;
    st[i] = acct;
    nsum[i] = 0.f;
}

// ---------- lean pipeline (uses lrbuf in d_ws) ----------

// K2: lr per (e,h) -> lrbuf; block-reduce running max -> atomicMax(gmax).
__global__ void edge_lr_max_kernel(const void* __restrict__ ei,
                                   const int* __restrict__ flag,
                                   const float* __restrict__ ss,
                                   const float* __restrict__ st,
                                   float* __restrict__ lrbuf,
                                   unsigned* __restrict__ gmax,
                                   int E) {
    __shared__ float red[256];
    int is64 = *flag;
    int n4 = E * 4;
    int stride = gridDim.x * blockDim.x;
    float lmax = -__builtin_inff();
    for (int i = blockIdx.x * blockDim.x + threadIdx.x; i < n4; i += stride) {
        int e = i >> 2, h = i & 3;
        int trg, src;
        load_edge(ei, is64, E, e, trg, src);
        float s = ss[src * 4 + h] + st[trg * 4 + h];
        float lr = s > 0.f ? s : NEG_SLOPE * s;
        lrbuf[i] = lr;
        lmax = fmaxf(lmax, lr);
    }
    red[threadIdx.x] = lmax;
    __syncthreads();
    for (int off = 128; off > 0; off >>= 1) {
        if (threadIdx.x < off)
            red[threadIdx.x] = fmaxf(red[threadIdx.x], red[threadIdx.x + off]);
        __syncthreads();
    }
    if (threadIdx.x == 0) atomicMax(gmax, fenc(red[0]));
}

// K3: p = exp(lr - c) (overwrites lrbuf in place), scatter-add into nsum.
__global__ void edge_exp_sum_lean_kernel(const void* __restrict__ ei,
                                         const int* __restrict__ flag,
                                         const unsigned* __restrict__ gmax,
                                         float* __restrict__ lrbuf,
                                         float* __restrict__ nsum,
                                         int E) {
    int is64 = *flag;
    float c = fdec(*gmax);
    int n4 = E * 4;
    int stride = gridDim.x * blockDim.x;
    for (int i = blockIdx.x * blockDim.x + threadIdx.x; i < n4; i += stride) {
        int trg = load_trg(ei, is64, i >> 2);
        float p = __expf(__builtin_nontemporal_load(&lrbuf[i]) - c);
        lrbuf[i] = p;   // numerator stored bit-exact as summed
        atomicAdd(&nsum[trg * 4 + (i & 3)], p);
    }
}

// K4: att = p / (nsum[trg,h] + eps). Nontemporal output store: don't let the
// output stream evict the hot tables from L2/L3.
__global__ void att_lean_kernel(const void* __restrict__ ei,
                                const int* __restrict__ flag,
                                const float* __restrict__ pbuf,
                                const float* __restrict__ nsum,
                                float* __restrict__ out,
                                int E) {
    int is64 = *flag;
    int n4 = E * 4;
    int stride = gridDim.x * blockDim.x;
    for (int i = blockIdx.x * blockDim.x + threadIdx.x; i < n4; i += stride) {
        int trg = load_trg(ei, is64, i >> 2);
        float p = __builtin_nontemporal_load(&pbuf[i]);
        float a = p / (nsum[trg * 4 + (i & 3)] + EPSV);
        __builtin_nontemporal_store(a, &out[i]);
    }
}

// ---------- fallback pipeline (r3, recompute; used only if ws too small) ----------

__device__ __forceinline__ float edge_lr_rc(const void* ei, int is64,
                                            const float* ss, const float* st,
                                            int E, int e, int h, int* trg_out) {
    int trg, src;
    load_edge(ei, is64, E, e, trg, src);
    if (trg_out) *trg_out = trg;
    float s = ss[src * 4 + h] + st[trg * 4 + h];
    return s > 0.f ? s : NEG_SLOPE * s;
}

__global__ void edge_max_fb_kernel(const void* __restrict__ ei,
                                   const int* __restrict__ flag,
                                   const float* __restrict__ ss,
                                   const float* __restrict__ st,
                                   unsigned* __restrict__ gmax, int E) {
    __shared__ float red[256];
    int is64 = *flag;
    int i = blockIdx.x * blockDim.x + threadIdx.x;
    float lr = -__builtin_inff();
    if (i < E * 4) lr = edge_lr_rc(ei, is64, ss, st, E, i >> 2, i & 3, nullptr);
    red[threadIdx.x] = lr;
    __syncthreads();
    for (int off = 128; off > 0; off >>= 1) {
        if (threadIdx.x < off)
            red[threadIdx.x] = fmaxf(red[threadIdx.x], red[threadIdx.x + off]);
        __syncthreads();
    }
    if (threadIdx.x == 0) atomicMax(gmax, fenc(red[0]));
}

__global__ void edge_exp_sum_fb_kernel(const void* __restrict__ ei,
                                       const int* __restrict__ flag,
                                       const float* __restrict__ ss,
                                       const float* __restrict__ st,
                                       const unsigned* __restrict__ gmax,
                                       float* __restrict__ nsum, int E) {
    int i = blockIdx.x * blockDim.x + threadIdx.x;
    if (i >= E * 4) return;
    int is64 = *flag;
    float c = fdec(*gmax);
    int trg;
    float lr = edge_lr_rc(ei, is64, ss, st, E, i >> 2, i & 3, &trg);
    atomicAdd(&nsum[trg * 4 + (i & 3)], __expf(lr - c));
}

__global__ void att_fb_kernel(const void* __restrict__ ei,
                              const int* __restrict__ flag,
                              const float* __restrict__ ss,
                              const float* __restrict__ st,
                              const unsigned* __restrict__ gmax,
                              const float* __restrict__ nsum,
                              float* __restrict__ out, int E) {
    int i = blockIdx.x * blockDim.x + threadIdx.x;
    if (i >= E * 4) return;
    int is64 = *flag;
    float c = fdec(*gmax);
    int trg;
    float lr = edge_lr_rc(ei, is64, ss, st, E, i >> 2, i & 3, &trg);
    float a = __expf(lr - c) / (nsum[trg * 4 + (i & 3)] + EPSV);
    __builtin_nontemporal_store(a, &out[i]);
}

// ---------- K5: feature gather ----------
// 32 lanes x 16B = 512B per edge, coalesced. Reads of the 25.6MB node table
// stay cacheable; output stores are nontemporal (clang ext vector type) so
// the 410MB write stream doesn't evict the table from L2/L3.
__global__ void gather_feat_kernel(const void* __restrict__ ei,
                                   const int* __restrict__ flag,
                                   const f32x4* __restrict__ nf4,
                                   f32x4* __restrict__ out4,
                                   int E) {
    int is64 = *flag;
    int n = E * 32;
    int stride = gridDim.x * blockDim.x;
    for (int t = blockIdx.x * blockDim.x + threadIdx.x; t < n; t += stride) {
        int e = t >> 5, q = t & 31;
        int src;
        if (is64) {
            src = (int)__builtin_nontemporal_load(&((const long long*)ei)[(size_t)E + e]);
        } else {
            src = __builtin_nontemporal_load(&((const int*)ei)[E + e]);
        }
        f32x4 v = nf4[(size_t)src * 32 + q];
        __builtin_nontemporal_store(v, &out4[(size_t)e * 32 + q]);
    }
}

extern "C" void kernel_launch(void* const* d_in, const int* in_sizes, int n_in,
                              void* d_out, int out_size, void* d_ws, size_t ws_size,
                              hipStream_t stream) {
    const float* nf  = (const float*)d_in[0];
    const float* sfs = (const float*)d_in[1];
    const float* sft = (const float*)d_in[2];
    const void*  ei  = d_in[3];

    const int NH = in_sizes[0] / 32;   // N*H (F = 32)
    const int E  = in_sizes[3] / 2;

    float* out = (float*)d_out;
    float* ws  = (float*)d_ws;
    float*    ss    = ws;
    float*    st    = ws + NH;
    float*    nsum  = ws + 2 * (size_t)NH;
    int*      flag  = (int*)(ws + 3 * (size_t)NH);
    unsigned* gmax  = (unsigned*)(flag + 1);
    float*    lrbuf = (float*)(gmax + 1);

    size_t need = ((size_t)3 * NH + 2 + (size_t)E * 4) * 4;
    bool lean = ws_size >= need;

    const int B = 256;
    const int n4 = E * 4;

    detect_idx_kernel<<<1, 256, 0, stream>>>((const unsigned*)ei, flag);

    node_scores_kernel<<<(NH + B - 1) / B, B, 0, stream>>>(nf, sfs, sft, ss, st,
                                                           nsum, gmax, NH);

    if (lean) {
        edge_lr_max_kernel<<<2048, B, 0, stream>>>(ei, flag, ss, st, lrbuf, gmax, E);
        edge_exp_sum_lean_kernel<<<2048, B, 0, stream>>>(ei, flag, gmax, lrbuf, nsum, E);
        att_lean_kernel<<<2048, B, 0, stream>>>(ei, flag, lrbuf, nsum, out, E);
    } else {
        edge_max_fb_kernel<<<(n4 + B - 1) / B, B, 0, stream>>>(ei, flag, ss, st, gmax, E);
        edge_exp_sum_fb_kernel<<<(n4 + B - 1) / B, B, 0, stream>>>(ei, flag, ss, st,
                                                                   gmax, nsum, E);
        att_fb_kernel<<<(n4 + B - 1) / B, B, 0, stream>>>(ei, flag, ss, st, gmax,
                                                          nsum, out, E);
    }

    gather_feat_kernel<<<4096, B, 0, stream>>>(
        ei, flag, (const f32x4*)nf, (f32x4*)(out + (size_t)E * 4), E);
}